// Round 1
// 213.326 us; speedup vs baseline: 1.4924x; 1.4924x over previous
//
#include <hip/hip_runtime.h>

#define N_NODES 50000
#define N_EDGES 800000
#define SCAN_NB 49   // ceil(50000 / 1024) blocks, 1024 elements per block

// -------- Kernel A: t = (h @ W) * norm ------------------------------------
__global__ __launch_bounds__(256) void gemm_scale_kernel(
    const float* __restrict__ h, const float* __restrict__ norm,
    const float* __restrict__ W, float* __restrict__ t)
{
    __shared__ float Ws[128 * 128];   // [k][c], 64 KB
    __shared__ float Hs[64 * 132];    // [r][k], padded stride 132, 33 KB
    const int tid = threadIdx.x;
    const int rbase = blockIdx.x * 64;

    const float4* Wg = (const float4*)W;
    float4* Ws4 = (float4*)Ws;
#pragma unroll
    for (int i = 0; i < 16; ++i)
        Ws4[i * 256 + tid] = Wg[i * 256 + tid];

#pragma unroll
    for (int i = 0; i < 8; ++i) {
        int f = i * 256 + tid;
        int row = f >> 5;
        int c = (f & 31) << 2;
        int gr = rbase + row;
        float4 v = make_float4(0.f, 0.f, 0.f, 0.f);
        if (gr < N_NODES) v = *(const float4*)(h + (size_t)gr * 128 + c);
        *(float4*)(Hs + row * 132 + c) = v;
    }
    __syncthreads();

    const int rt = tid >> 5, ct = tid & 31;
    const int r0 = rt * 8, c0 = ct * 4;
    float acc[8][4];
#pragma unroll
    for (int i = 0; i < 8; ++i)
#pragma unroll
        for (int j = 0; j < 4; ++j) acc[i][j] = 0.f;

    for (int k = 0; k < 128; k += 4) {
        float4 w0 = *(const float4*)(Ws + (k + 0) * 128 + c0);
        float4 w1 = *(const float4*)(Ws + (k + 1) * 128 + c0);
        float4 w2 = *(const float4*)(Ws + (k + 2) * 128 + c0);
        float4 w3 = *(const float4*)(Ws + (k + 3) * 128 + c0);
#pragma unroll
        for (int i = 0; i < 8; ++i) {
            float4 hv = *(const float4*)(Hs + (r0 + i) * 132 + k);
            acc[i][0] += hv.x * w0.x + hv.y * w1.x + hv.z * w2.x + hv.w * w3.x;
            acc[i][1] += hv.x * w0.y + hv.y * w1.y + hv.z * w2.y + hv.w * w3.y;
            acc[i][2] += hv.x * w0.z + hv.y * w1.z + hv.z * w2.z + hv.w * w3.z;
            acc[i][3] += hv.x * w0.w + hv.y * w1.w + hv.z * w2.w + hv.w * w3.w;
        }
    }

#pragma unroll
    for (int i = 0; i < 8; ++i) {
        int gr = rbase + r0 + i;
        if (gr < N_NODES) {
            float nv = norm[gr];
            float4 v = make_float4(acc[i][0] * nv, acc[i][1] * nv,
                                   acc[i][2] * nv, acc[i][3] * nv);
            *(float4*)(t + (size_t)gr * 128 + c0) = v;
        }
    }
}

// -------- CSR build step 1: in-degree histogram ---------------------------
__global__ __launch_bounds__(256) void hist_kernel(
    const int* __restrict__ dst, int* __restrict__ cnt)
{
    int e = blockIdx.x * blockDim.x + threadIdx.x;
    if (e < N_EDGES) atomicAdd(&cnt[dst[e]], 1);
}

// -------- CSR build step 2a: per-block sums (coalesced int4) --------------
// 49 blocks x 256 threads; each thread sums 4 consecutive ints.
__global__ __launch_bounds__(256) void scan_sums_kernel(
    const int* __restrict__ cnt, int* __restrict__ bsum)
{
    const int tid = threadIdx.x;
    const int idx = blockIdx.x * 1024 + tid * 4;
    int s = 0;
    if (idx < N_NODES) {                 // 50000 % 4 == 0: group fully in-range
        int4 v = *(const int4*)(cnt + idx);
        s = v.x + v.y + v.z + v.w;
    }
    // wave-64 reduce
#pragma unroll
    for (int d = 32; d > 0; d >>= 1) s += __shfl_down(s, d);
    __shared__ int ws[4];
    if ((tid & 63) == 0) ws[tid >> 6] = s;
    __syncthreads();
    if (tid == 0) bsum[blockIdx.x] = ws[0] + ws[1] + ws[2] + ws[3];
}

// -------- CSR build step 2b: exclusive scan of 49 block sums (1 wave) -----
__global__ __launch_bounds__(64) void scan_bsum_kernel(
    const int* __restrict__ bsum, int* __restrict__ boff)
{
    const int tid = threadIdx.x;
    int v = (tid < SCAN_NB) ? bsum[tid] : 0;
    int inc = v;
#pragma unroll
    for (int d = 1; d < 64; d <<= 1) {
        int u = __shfl_up(inc, d);
        if (tid >= d) inc += u;
    }
    if (tid < SCAN_NB) boff[tid] = inc - v;   // exclusive prefix
}

// -------- CSR build step 2c: block-local scan + write off/cur -------------
__global__ __launch_bounds__(256) void scan_write_kernel(
    const int* __restrict__ cnt, const int* __restrict__ boff,
    int* __restrict__ off, int* __restrict__ cur)
{
    const int tid = threadIdx.x;
    const int idx = blockIdx.x * 1024 + tid * 4;

    int4 v = make_int4(0, 0, 0, 0);
    if (idx < N_NODES) v = *(const int4*)(cnt + idx);
    const int s = v.x + v.y + v.z + v.w;

    // inclusive scan of s within the wave
    const int lane = tid & 63, w = tid >> 6;
    int inc = s;
#pragma unroll
    for (int d = 1; d < 64; d <<= 1) {
        int u = __shfl_up(inc, d);
        if (lane >= d) inc += u;
    }
    __shared__ int wsum[4];
    if (lane == 63) wsum[w] = inc;
    __syncthreads();
    int woff = 0;
    for (int i = 0; i < w; ++i) woff += wsum[i];

    // exclusive prefix for this thread's first element
    int o0 = boff[blockIdx.x] + woff + inc - s;
    int o1 = o0 + v.x;
    int o2 = o1 + v.y;
    int o3 = o2 + v.z;

    if (idx < N_NODES) {
        int4 ov = make_int4(o0, o1, o2, o3);
        *(int4*)(off + idx) = ov;
        *(int4*)(cur + idx) = ov;
    }
    if (blockIdx.x == 0 && tid == 0) off[N_NODES] = N_EDGES;  // total degree
}

// -------- CSR build step 3: fill edge-source lists ------------------------
__global__ __launch_bounds__(256) void fill_kernel(
    const int* __restrict__ src, const int* __restrict__ dst,
    int* __restrict__ cur, int* __restrict__ esrc)
{
    int e = blockIdx.x * blockDim.x + threadIdx.x;
    if (e < N_EDGES) {
        int p = atomicAdd(&cur[dst[e]], 1);
        esrc[p] = src[e];
    }
}

// -------- Kernel D: gather-aggregate + fused finalize ---------------------
// 32 lanes per dst node; lane l owns float4 column l. No atomics.
__global__ __launch_bounds__(256) void aggregate_kernel(
    const int* __restrict__ off, const int* __restrict__ esrc,
    const float* __restrict__ t, const float* __restrict__ norm,
    const float* __restrict__ b, float* __restrict__ out)
{
    const int g = blockIdx.x * 8 + (threadIdx.x >> 5);
    if (g >= N_NODES) return;
    const int l = threadIdx.x & 31;
    const int c = l << 2;
    const int i0 = off[g], i1 = off[g + 1];

    float4 acc = make_float4(0.f, 0.f, 0.f, 0.f);
    for (int i = i0; i < i1; ++i) {
        int s = esrc[i];
        float4 v = *(const float4*)(t + (size_t)s * 128 + c);
        acc.x += v.x; acc.y += v.y; acc.z += v.z; acc.w += v.w;
    }
    const float nv = norm[g];
    const float4 bv = ((const float4*)b)[l];
    float4 o = make_float4(acc.x * nv + bv.x, acc.y * nv + bv.y,
                           acc.z * nv + bv.z, acc.w * nv + bv.w);
    *(float4*)(out + (size_t)g * 128 + c) = o;
}

static inline size_t align256(size_t x) { return (x + 255) & ~(size_t)255; }

extern "C" void kernel_launch(void* const* d_in, const int* in_sizes, int n_in,
                              void* d_out, int out_size, void* d_ws, size_t ws_size,
                              hipStream_t stream)
{
    const float* h    = (const float*)d_in[0];
    const float* norm = (const float*)d_in[1];
    const float* W    = (const float*)d_in[2];
    const float* b    = (const float*)d_in[3];
    const int*   src  = (const int*)d_in[4];
    const int*   dst  = (const int*)d_in[5];
    float* out = (float*)d_out;

    // workspace layout
    char* ws = (char*)d_ws;
    size_t o = 0;
    float* t = (float*)(ws + o);            o = align256(o + (size_t)N_NODES * 128 * 4);
    int* cnt = (int*)(ws + o);              o = align256(o + (size_t)N_NODES * 4);
    int* off = (int*)(ws + o);              o = align256(o + (size_t)(N_NODES + 1) * 4);
    int* cur = (int*)(ws + o);              o = align256(o + (size_t)N_NODES * 4);
    int* esrc = (int*)(ws + o);             o = align256(o + (size_t)N_EDGES * 4);
    int* bsum = (int*)(ws + o);             o = align256(o + (size_t)SCAN_NB * 4);
    int* boff = (int*)(ws + o);             o = align256(o + (size_t)SCAN_NB * 4);

    // zero the degree histogram every call (deterministic rebuild)
    hipMemsetAsync(cnt, 0, (size_t)N_NODES * 4, stream);

    gemm_scale_kernel<<<(N_NODES + 63) / 64, 256, 0, stream>>>(h, norm, W, t);
    hist_kernel<<<(N_EDGES + 255) / 256, 256, 0, stream>>>(dst, cnt);
    scan_sums_kernel<<<SCAN_NB, 256, 0, stream>>>(cnt, bsum);
    scan_bsum_kernel<<<1, 64, 0, stream>>>(bsum, boff);
    scan_write_kernel<<<SCAN_NB, 256, 0, stream>>>(cnt, boff, off, cur);
    fill_kernel<<<(N_EDGES + 255) / 256, 256, 0, stream>>>(src, dst, cur, esrc);
    aggregate_kernel<<<(N_NODES + 7) / 8, 256, 0, stream>>>(off, esrc, t, norm, b, out);
}